// Round 9
// baseline (174.789 us; speedup 1.0000x reference)
//
#include <hip/hip_runtime.h>
#include <hip/hip_cooperative_groups.h>
#include <stdint.h>

namespace cg = cooperative_groups;

#define KBOX 1024
#define EPSF 1e-4f
#define SLACK 3e-5f
#define NBLK (KBOX / 2)  // block b owns rows {b, 1023-b}

// ws: cnt[1024] u32 at offset 0 (fully written each call before any read)

// double-precision analytic inverse of the affine 3x4 (rows of A) -> 12 floats
__device__ inline void inv_affine(const float r[12], float* o) {
    double m00 = r[0], m01 = r[1], m02 = r[2];
    double m10 = r[4], m11 = r[5], m12 = r[6];
    double m20 = r[8], m21 = r[9], m22 = r[10];
    double c00 = m11 * m22 - m12 * m21;
    double c01 = m12 * m20 - m10 * m22;
    double c02 = m10 * m21 - m11 * m20;
    double det = m00 * c00 + m01 * c01 + m02 * c02;
    double id = 1.0 / det;
    double i00 = c00 * id, i01 = (m02 * m21 - m01 * m22) * id, i02 = (m01 * m12 - m02 * m11) * id;
    double i10 = c01 * id, i11 = (m00 * m22 - m02 * m20) * id, i12 = (m02 * m10 - m00 * m12) * id;
    double i20 = c02 * id, i21 = (m01 * m20 - m00 * m21) * id, i22 = (m00 * m11 - m01 * m10) * id;
    double tx = r[3], ty = r[7], tz = r[11];
    o[0] = (float)i00; o[1] = (float)i01; o[2] = (float)i02;
    o[3] = (float)(-(i00 * tx + i01 * ty + i02 * tz));
    o[4] = (float)i10; o[5] = (float)i11; o[6] = (float)i12;
    o[7] = (float)(-(i10 * tx + i11 * ty + i12 * tz));
    o[8] = (float)i20; o[9] = (float)i21; o[10] = (float)i22;
    o[11] = (float)(-(i20 * tx + i21 * ty + i22 * tz));
}

__global__ void k_all(const float* __restrict__ bbmin, const float* __restrict__ bbmax,
                      const float* __restrict__ A, const uint8_t* __restrict__ disB,
                      float* __restrict__ out_hposed, float* __restrict__ out_pairs,
                      uint32_t* __restrict__ cnt) {
    int b = blockIdx.x, t = threadIdx.x;
    int lane = t & 63, wave = t >> 6;
    int kk[2]; kk[0] = b; kk[1] = (KBOX - 1) - b;

    __shared__ float bk[2][12], hkS[2][24], bneS[2][3], bxeS[2][3], wmnS[2][3], wmxS[2][3];
    __shared__ uint64_t words[2][16];
    __shared__ uint32_t rcnt[2];
    __shared__ uint32_t partial[4][2];
    __shared__ int flagS;

    // ---- phase A: fill this block's slice of the pair region (-1) ----
    float4* fillp = (float4*)out_pairs;
#pragma unroll
    for (int i = 0; i < 4; ++i)
        fillp[(size_t)b * 1024 + i * 256 + t] = make_float4(-1.f, -1.f, -1.f, -1.f);

    if (t < 32) words[t >> 4][t & 15] = 0ull;
    if (t < 2) rcnt[t] = 0;

    // dis layout detect: wave 0 scans first 256 B (int32 0/1 data has all
    // high bytes zero; random bools don't — false-neg prob ~2^-192)
    if (wave == 0) {
        uint32_t dw = ((const uint32_t*)disB)[lane];
        uint64_t bal = __ballot((dw & 0xFFFFFF00u) != 0 ? 1 : 0);
        if (lane == 0) flagS = (bal != 0ull);
    }
    // two parallel prep threads (one per owned row), in different waves
    if (t == 16 || t == 80) {
        int ri = (t == 80);
        int k = kk[ri];
        float rk[12];
#pragma unroll
        for (int i = 0; i < 3; ++i) {
            float4 a4 = *(const float4*)(A + (size_t)k * 16 + i * 4);
            rk[i * 4 + 0] = a4.x; rk[i * 4 + 1] = a4.y; rk[i * 4 + 2] = a4.z; rk[i * 4 + 3] = a4.w;
        }
        inv_affine(rk, bk[ri]);
        float bmn[3], bmx[3];
#pragma unroll
        for (int i = 0; i < 3; ++i) { bmn[i] = bbmin[k * 3 + i]; bmx[i] = bbmax[k * 3 + i]; }
#pragma unroll
        for (int i = 0; i < 3; ++i) { bneS[ri][i] = bmn[i] + EPSF; bxeS[ri][i] = bmx[i] - EPSF; }
        float wn[3] = {1e30f, 1e30f, 1e30f}, wx[3] = {-1e30f, -1e30f, -1e30f};
#pragma unroll
        for (int c = 0; c < 8; ++c) {
            float cx = ((c >> 2) & 1) ? bmx[0] : bmn[0];
            float cy = ((c >> 1) & 1) ? bmx[1] : bmn[1];
            float cz = (c & 1) ? bmx[2] : bmn[2];
#pragma unroll
            for (int i = 0; i < 3; ++i) {
                float p = rk[i * 4 + 0] * cx + rk[i * 4 + 1] * cy + rk[i * 4 + 2] * cz + rk[i * 4 + 3];
                hkS[ri][c * 3 + i] = p;
                wn[i] = fminf(wn[i], p);
                wx[i] = fmaxf(wx[i], p);
            }
        }
#pragma unroll
        for (int i = 0; i < 3; ++i) { wmnS[ri][i] = wn[i] - SLACK; wmxS[ri][i] = wx[i] + SLACK; }
    }
    __syncthreads();
    const bool isBool = flagS != 0;

    // output 0 (hposed) straight from LDS
    if (t < 24) out_hposed[(size_t)kk[0] * 24 + t] = hkS[0][t];
    if (t >= 64 && t < 88) out_hposed[(size_t)kk[1] * 24 + (t - 64)] = hkS[1][t - 64];

    int nct = (kk[1] >> 8) + 1;  // kk[1] >= 512 -> 3 or 4 col tiles
    for (int ct = 0; ct < nct; ++ct) {
        int l = ct * 256 + t;
        float rl[12];
#pragma unroll
        for (int i = 0; i < 3; ++i) {
            float4 a4 = *(const float4*)(A + (size_t)l * 16 + i * 4);
            rl[i * 4 + 0] = a4.x; rl[i * 4 + 1] = a4.y; rl[i * 4 + 2] = a4.z; rl[i * 4 + 3] = a4.w;
        }
        float bmnl[3], bmxl[3];
#pragma unroll
        for (int i = 0; i < 3; ++i) { bmnl[i] = bbmin[l * 3 + i]; bmxl[i] = bbmax[l * 3 + i]; }
        float wcl[3], whl[3];
        {
            float cx = 0.5f * (bmnl[0] + bmxl[0]), hx = 0.5f * (bmxl[0] - bmnl[0]);
            float cy = 0.5f * (bmnl[1] + bmxl[1]), hy = 0.5f * (bmxl[1] - bmnl[1]);
            float cz = 0.5f * (bmnl[2] + bmxl[2]), hz = 0.5f * (bmxl[2] - bmnl[2]);
#pragma unroll
            for (int i = 0; i < 3; ++i) {
                wcl[i] = rl[i * 4 + 0] * cx + rl[i * 4 + 1] * cy + rl[i * 4 + 2] * cz + rl[i * 4 + 3];
                whl[i] = fabsf(rl[i * 4 + 0]) * hx + fabsf(rl[i * 4 + 1]) * hy + fabsf(rl[i * 4 + 2]) * hz;
            }
        }
        for (int ri = 0; ri < 2; ++ri) {
            int k = kk[ri];
            if (ct * 256 > k) continue;  // block-uniform; LDS words pre-zeroed
            bool cand = false;
            if (l <= k) {
                cand = (wcl[0] - whl[0] <= wmxS[ri][0]) & (wmnS[ri][0] <= wcl[0] + whl[0]) &
                       (wcl[1] - whl[1] <= wmxS[ri][1]) & (wmnS[ri][1] <= wcl[1] + whl[1]) &
                       (wcl[2] - whl[2] <= wmxS[ri][2]) & (wmnS[ri][2] <= wcl[2] + whl[2]);
            }
            bool bit = false, dA = false, dB = false;
            if (cand) {  // dis bits only for AABB candidates (~1% of pairs)
                if (isBool) {
                    dA = disB[(size_t)k * KBOX + l] != 0;
                    dB = disB[(size_t)l * KBOX + k] != 0;
                } else {
                    const int* disI = (const int*)disB;
                    dA = disI[(size_t)k * KBOX + l] != 0;
                    dB = disI[(size_t)l * KBOX + k] != 0;
                }
            }
            if (cand && (dA | dB)) {
                float hl[24];  // corners of l, only on this rare path
#pragma unroll
                for (int c = 0; c < 8; ++c) {
                    float cx = ((c >> 2) & 1) ? bmxl[0] : bmnl[0];
                    float cy = ((c >> 1) & 1) ? bmxl[1] : bmnl[1];
                    float cz = (c & 1) ? bmxl[2] : bmnl[2];
#pragma unroll
                    for (int i = 0; i < 3; ++i)
                        hl[c * 3 + i] = rl[i * 4 + 0] * cx + rl[i * 4 + 1] * cy +
                                        rl[i * 4 + 2] * cz + rl[i * 4 + 3];
                }
                if (dA) {  // corners of l into frame k
                    bool rawA = false;
#pragma unroll
                    for (int c = 0; c < 8; ++c) {
                        float px = hl[c * 3 + 0], py = hl[c * 3 + 1], pz = hl[c * 3 + 2];
                        float x = bk[ri][0] * px + bk[ri][1] * py + bk[ri][2] * pz + bk[ri][3];
                        float y = bk[ri][4] * px + bk[ri][5] * py + bk[ri][6] * pz + bk[ri][7];
                        float z = bk[ri][8] * px + bk[ri][9] * py + bk[ri][10] * pz + bk[ri][11];
                        rawA = rawA || (x > bneS[ri][0] && x < bxeS[ri][0] &&
                                        y > bneS[ri][1] && y < bxeS[ri][1] &&
                                        z > bneS[ri][2] && z < bxeS[ri][2]);
                    }
                    bit = rawA;
                }
                if (dB && !bit) {  // corners of k into frame l (inverse on demand)
                    float bl[12];
                    inv_affine(rl, bl);
                    bool rawB = false;
#pragma unroll
                    for (int c = 0; c < 8; ++c) {
                        float px = hkS[ri][c * 3 + 0], py = hkS[ri][c * 3 + 1], pz = hkS[ri][c * 3 + 2];
                        float x = bl[0] * px + bl[1] * py + bl[2] * pz + bl[3];
                        float y = bl[4] * px + bl[5] * py + bl[6] * pz + bl[7];
                        float z = bl[8] * px + bl[9] * py + bl[10] * pz + bl[11];
                        rawB = rawB || (x > bmnl[0] + EPSF && x < bmxl[0] - EPSF &&
                                        y > bmnl[1] + EPSF && y < bmxl[1] - EPSF &&
                                        z > bmnl[2] + EPSF && z < bmxl[2] - EPSF);
                    }
                    bit = rawB;
                }
            }
            uint64_t word = __ballot(bit ? 1 : 0);
            if (lane == 0) {
                words[ri][ct * 4 + wave] = word;
                if (word) atomicAdd(&rcnt[ri], (uint32_t)__popcll(word));
            }
        }
    }
    __syncthreads();
    if (t < 2) cnt[kk[t]] = rcnt[t];
    __threadfence();
    cg::this_grid().sync();

    // ---- phase B: prefix over cnt[] + compact both owned rows ----
    uint32_t s1 = 0, s2 = 0;
    for (int idx = t; idx < KBOX; idx += 256) {
        uint32_t v = cnt[idx];
        s1 += (idx < kk[0]) ? v : 0u;
        s2 += (idx < kk[1]) ? v : 0u;
    }
#pragma unroll
    for (int off = 32; off > 0; off >>= 1) {
        s1 += __shfl_xor(s1, off);
        s2 += __shfl_xor(s2, off);
    }
    if (lane == 0) { partial[wave][0] = s1; partial[wave][1] = s2; }
    __syncthreads();
    if (wave < 2) {  // wave 0 -> row kk[0], wave 1 -> row kk[1]
        uint32_t start = partial[0][wave] + partial[1][wave] + partial[2][wave] + partial[3][wave];
        int k = kk[wave];
        uint64_t w = (lane < 16) ? words[wave][lane] : 0ull;
        int c = (int)__popcll(w);
        int p = c;
#pragma unroll
        for (int off = 1; off < 64; off <<= 1) {
            int u = __shfl_up(p, off);
            if (lane >= off) p += u;
        }
        int ofs = (int)start + (p - c);
        float fk = (float)k;
        while (w) {
            int bpos = __builtin_ctzll(w);
            int col = lane * 64 + bpos;
            out_pairs[2 * (size_t)ofs + 0] = (float)col;  // min = col (tril => col <= row)
            out_pairs[2 * (size_t)ofs + 1] = fk;          // max = row
            ++ofs;
            w &= w - 1;
        }
    }
}

extern "C" void kernel_launch(void* const* d_in, const int* in_sizes, int n_in,
                              void* d_out, int out_size, void* d_ws, size_t ws_size,
                              hipStream_t stream) {
    const float* bbmin = (const float*)d_in[0];
    const float* bbmax = (const float*)d_in[1];
    const float* A = (const float*)d_in[2];
    const uint8_t* dis = (const uint8_t*)d_in[3];
    float* out_hposed = (float*)d_out;
    float* out_pairs = (float*)d_out + KBOX * 24;
    uint32_t* cnt = (uint32_t*)d_ws;

    void* args[] = {(void*)&bbmin, (void*)&bbmax, (void*)&A, (void*)&dis,
                    (void*)&out_hposed, (void*)&out_pairs, (void*)&cnt};
    hipLaunchCooperativeKernel((const void*)k_all, dim3(NBLK), dim3(256), args, 0, stream);
}

// Round 12
// 23.891 us; speedup vs baseline: 7.3162x; 7.3162x over previous
//
#include <hip/hip_runtime.h>
#include <stdint.h>

#define KBOX 1024
#define EPSF 1e-4f
#define SLACK 3e-5f
#define TILE_BLOCKS 4096   // (row k, 256-col tile j): bid = k*4 + j
#define FILL_BLOCKS 2048   // 2048*256 float4 = 2*K*K floats
#define POSE_BLOCKS 4      // 4*256 = 1024 boxes -> hposed output

// ws layout (bytes):
//   0      : bm [K][16] u64    (128 KB) inside bitmask words
//   131072 : tileCnt [K][4] u32 (16 KB)  per (row, col-tile) count
#define BM_OFF 0
#define TC_OFF 131072

// double-precision analytic inverse of the affine 3x4 (rows of A) -> 12 floats
__device__ inline void inv_affine(const float r[12], float* o) {
    double m00 = r[0], m01 = r[1], m02 = r[2];
    double m10 = r[4], m11 = r[5], m12 = r[6];
    double m20 = r[8], m21 = r[9], m22 = r[10];
    double c00 = m11 * m22 - m12 * m21;
    double c01 = m12 * m20 - m10 * m22;
    double c02 = m10 * m21 - m11 * m20;
    double det = m00 * c00 + m01 * c01 + m02 * c02;
    double id = 1.0 / det;
    double i00 = c00 * id, i01 = (m02 * m21 - m01 * m22) * id, i02 = (m01 * m12 - m02 * m11) * id;
    double i10 = c01 * id, i11 = (m00 * m22 - m02 * m20) * id, i12 = (m02 * m10 - m00 * m12) * id;
    double i20 = c02 * id, i21 = (m01 * m20 - m00 * m21) * id, i22 = (m00 * m11 - m01 * m10) * id;
    double tx = r[3], ty = r[7], tz = r[11];
    o[0] = (float)i00; o[1] = (float)i01; o[2] = (float)i02;
    o[3] = (float)(-(i00 * tx + i01 * ty + i02 * tz));
    o[4] = (float)i10; o[5] = (float)i11; o[6] = (float)i12;
    o[7] = (float)(-(i10 * tx + i11 * ty + i12 * tz));
    o[8] = (float)i20; o[9] = (float)i21; o[10] = (float)i22;
    o[11] = (float)(-(i20 * tx + i21 * ty + i22 * tz));
}

__global__ void k_main(const float* __restrict__ bbmin, const float* __restrict__ bbmax,
                       const float* __restrict__ A, const uint8_t* __restrict__ disB,
                       float* __restrict__ out_hposed, float* __restrict__ out_pairs,
                       uint64_t* __restrict__ bm, uint32_t* __restrict__ tileCnt) {
    int bid = blockIdx.x;
    int t = threadIdx.x;

    if (bid >= TILE_BLOCKS) {  // pose blocks: write hposed (output 0)
        int k = (bid - TILE_BLOCKS) * 256 + t;
        float r[12];
#pragma unroll
        for (int i = 0; i < 3; ++i) {
            float4 a4 = *(const float4*)(A + (size_t)k * 16 + i * 4);
            r[i * 4 + 0] = a4.x; r[i * 4 + 1] = a4.y; r[i * 4 + 2] = a4.z; r[i * 4 + 3] = a4.w;
        }
        float bmn[3], bmx[3];
#pragma unroll
        for (int i = 0; i < 3; ++i) { bmn[i] = bbmin[k * 3 + i]; bmx[i] = bbmax[k * 3 + i]; }
#pragma unroll
        for (int c = 0; c < 8; ++c) {
            float cx = ((c >> 2) & 1) ? bmx[0] : bmn[0];
            float cy = ((c >> 1) & 1) ? bmx[1] : bmn[1];
            float cz = (c & 1) ? bmx[2] : bmn[2];
#pragma unroll
            for (int i = 0; i < 3; ++i)
                out_hposed[(size_t)k * 24 + c * 3 + i] =
                    r[i * 4 + 0] * cx + r[i * 4 + 1] * cy + r[i * 4 + 2] * cz + r[i * 4 + 3];
        }
        return;
    }

    // ---- tile block: row k, cols j*256..j*256+255 ----
    int k = bid >> 2, j = bid & 3;
    int lane = t & 63, wave = t >> 6;
    bool active = (j * 256 <= k);
    int l = j * 256 + t;

    // issue long-latency col loads FIRST (independent of the fill store)
    float rl[12];
    float bmnl[3], bmxl[3];
    if (active) {
#pragma unroll
        for (int i = 0; i < 3; ++i) {
            float4 a4 = *(const float4*)(A + (size_t)l * 16 + i * 4);
            rl[i * 4 + 0] = a4.x; rl[i * 4 + 1] = a4.y; rl[i * 4 + 2] = a4.z; rl[i * 4 + 3] = a4.w;
        }
#pragma unroll
        for (int i = 0; i < 3; ++i) { bmnl[i] = bbmin[l * 3 + i]; bmxl[i] = bbmax[l * 3 + i]; }
    }

    // fill this block's 2KB slice of the pair region with -1 (all 256 lanes)
    ((float2*)out_pairs)[(size_t)bid * 256 + t] = make_float2(-1.f, -1.f);

    __shared__ float bk[12], hkS[24], bneS[3], bxeS[3], wmnS[3], wmxS[3];
    __shared__ uint32_t cntS;
    __shared__ int flagS;

    if (!active) {
        if (t == 0) tileCnt[bid] = 0;
        return;
    }

    // dis layout detect: wave 0 scans first 256 B (int32 0/1 data has all
    // high bytes zero; random bools don't)
    if (wave == 0) {
        uint32_t dw = ((const uint32_t*)disB)[lane];
        uint64_t bal = __ballot((dw & 0xFFFFFF00u) != 0 ? 1 : 0);
        if (lane == 0) flagS = (bal != 0ull);
    }
    if (t == 0) {  // row prep
        cntS = 0;
        float rk[12];
#pragma unroll
        for (int i = 0; i < 3; ++i) {
            float4 a4 = *(const float4*)(A + (size_t)k * 16 + i * 4);
            rk[i * 4 + 0] = a4.x; rk[i * 4 + 1] = a4.y; rk[i * 4 + 2] = a4.z; rk[i * 4 + 3] = a4.w;
        }
        inv_affine(rk, bk);
        float bmn[3], bmx[3];
#pragma unroll
        for (int i = 0; i < 3; ++i) { bmn[i] = bbmin[k * 3 + i]; bmx[i] = bbmax[k * 3 + i]; }
#pragma unroll
        for (int i = 0; i < 3; ++i) { bneS[i] = bmn[i] + EPSF; bxeS[i] = bmx[i] - EPSF; }
        float wn[3] = {1e30f, 1e30f, 1e30f}, wx[3] = {-1e30f, -1e30f, -1e30f};
#pragma unroll
        for (int c = 0; c < 8; ++c) {
            float cx = ((c >> 2) & 1) ? bmx[0] : bmn[0];
            float cy = ((c >> 1) & 1) ? bmx[1] : bmn[1];
            float cz = (c & 1) ? bmx[2] : bmn[2];
#pragma unroll
            for (int i = 0; i < 3; ++i) {
                float p = rk[i * 4 + 0] * cx + rk[i * 4 + 1] * cy + rk[i * 4 + 2] * cz + rk[i * 4 + 3];
                hkS[c * 3 + i] = p;
                wn[i] = fminf(wn[i], p);
                wx[i] = fmaxf(wx[i], p);
            }
        }
#pragma unroll
        for (int i = 0; i < 3; ++i) { wmnS[i] = wn[i] - SLACK; wmxS[i] = wx[i] + SLACK; }
    }

    // cheap world AABB of col box (|R|·h form)
    float wcl[3], whl[3];
    {
        float cx = 0.5f * (bmnl[0] + bmxl[0]), hx = 0.5f * (bmxl[0] - bmnl[0]);
        float cy = 0.5f * (bmnl[1] + bmxl[1]), hy = 0.5f * (bmxl[1] - bmnl[1]);
        float cz = 0.5f * (bmnl[2] + bmxl[2]), hz = 0.5f * (bmxl[2] - bmnl[2]);
#pragma unroll
        for (int i = 0; i < 3; ++i) {
            wcl[i] = rl[i * 4 + 0] * cx + rl[i * 4 + 1] * cy + rl[i * 4 + 2] * cz + rl[i * 4 + 3];
            whl[i] = fabsf(rl[i * 4 + 0]) * hx + fabsf(rl[i * 4 + 1]) * hy + fabsf(rl[i * 4 + 2]) * hz;
        }
    }
    __syncthreads();
    const bool isBool = flagS != 0;

    bool cand = false;
    if (l <= k) {
        cand = (wcl[0] - whl[0] <= wmxS[0]) & (wmnS[0] <= wcl[0] + whl[0]) &
               (wcl[1] - whl[1] <= wmxS[1]) & (wmnS[1] <= wcl[1] + whl[1]) &
               (wcl[2] - whl[2] <= wmxS[2]) & (wmnS[2] <= wcl[2] + whl[2]);
    }
    bool bit = false, dA = false, dB = false;
    if (cand) {  // dis bits only for AABB candidates (~1% of pairs)
        if (isBool) {
            dA = disB[(size_t)k * KBOX + l] != 0;
            dB = disB[(size_t)l * KBOX + k] != 0;
        } else {
            const int* disI = (const int*)disB;
            dA = disI[(size_t)k * KBOX + l] != 0;
            dB = disI[(size_t)l * KBOX + k] != 0;
        }
    }
    if (cand && (dA | dB)) {
        float hl[24];  // corners of l, only on this rare path
#pragma unroll
        for (int c = 0; c < 8; ++c) {
            float cx = ((c >> 2) & 1) ? bmxl[0] : bmnl[0];
            float cy = ((c >> 1) & 1) ? bmxl[1] : bmnl[1];
            float cz = (c & 1) ? bmxl[2] : bmnl[2];
#pragma unroll
            for (int i = 0; i < 3; ++i)
                hl[c * 3 + i] = rl[i * 4 + 0] * cx + rl[i * 4 + 1] * cy +
                                rl[i * 4 + 2] * cz + rl[i * 4 + 3];
        }
        if (dA) {  // corners of l into frame k
            bool rawA = false;
#pragma unroll
            for (int c = 0; c < 8; ++c) {
                float px = hl[c * 3 + 0], py = hl[c * 3 + 1], pz = hl[c * 3 + 2];
                float x = bk[0] * px + bk[1] * py + bk[2] * pz + bk[3];
                float y = bk[4] * px + bk[5] * py + bk[6] * pz + bk[7];
                float z = bk[8] * px + bk[9] * py + bk[10] * pz + bk[11];
                rawA = rawA || (x > bneS[0] && x < bxeS[0] && y > bneS[1] && y < bxeS[1] &&
                                z > bneS[2] && z < bxeS[2]);
            }
            bit = rawA;
        }
        if (dB && !bit) {  // corners of k into frame l (inverse on demand)
            float bl[12];
            inv_affine(rl, bl);
            bool rawB = false;
#pragma unroll
            for (int c = 0; c < 8; ++c) {
                float px = hkS[c * 3 + 0], py = hkS[c * 3 + 1], pz = hkS[c * 3 + 2];
                float x = bl[0] * px + bl[1] * py + bl[2] * pz + bl[3];
                float y = bl[4] * px + bl[5] * py + bl[6] * pz + bl[7];
                float z = bl[8] * px + bl[9] * py + bl[10] * pz + bl[11];
                rawB = rawB || (x > bmnl[0] + EPSF && x < bmxl[0] - EPSF &&
                                y > bmnl[1] + EPSF && y < bmxl[1] - EPSF &&
                                z > bmnl[2] + EPSF && z < bmxl[2] - EPSF);
            }
            bit = rawB;
        }
    }
    uint64_t word = __ballot(bit ? 1 : 0);
    if (lane == 0) {
        bm[(size_t)k * 16 + j * 4 + wave] = word;
        if (word) atomicAdd(&cntS, (uint32_t)__popcll(word));
    }
    __syncthreads();
    if (t == 0) tileCnt[bid] = cntS;
}

__global__ void k_compact(const uint64_t* __restrict__ bm,
                          const uint32_t* __restrict__ tileCnt, float* __restrict__ out) {
    int k = blockIdx.x;
    int t = threadIdx.x;  // 256 threads
    int wave = t >> 6, lane = t & 63;
    __shared__ uint32_t ws4[4];
    // start = sum of row counts for rows < k. Constant trip count (4 uint4 row
    // loads per thread, unrolled -> all loads in flight; the old data-dependent
    // loop serialized up to 16 L2 latencies).
    uint32_t s = 0;
#pragma unroll
    for (int rr = 0; rr < 4; ++rr) {
        int row = t + rr * 256;
        uint4 c4 = *(const uint4*)(tileCnt + (size_t)row * 4);
        uint32_t v = c4.x + c4.y + c4.z + c4.w;
        s += (row < k) ? v : 0u;
    }
#pragma unroll
    for (int off = 32; off > 0; off >>= 1) s += __shfl_xor(s, off);
    if (lane == 0) ws4[wave] = s;
    __syncthreads();
    if (t >= 64) return;  // wave 0 finishes the row
    uint32_t start = ws4[0] + ws4[1] + ws4[2] + ws4[3];

    // only words with t*64 <= k are written by k_main; mask the rest
    uint64_t w = (t < 16 && t * 64 <= k) ? bm[(size_t)k * 16 + t] : 0ull;
    int c = (int)__popcll(w);
    int p = c;
#pragma unroll
    for (int off = 1; off < 64; off <<= 1) {
        int u = __shfl_up(p, off);
        if (t >= off) p += u;
    }
    int ofs = (int)start + (p - c);
    float fk = (float)k;
    while (w) {
        int b = __builtin_ctzll(w);
        int col = t * 64 + b;
        out[2 * (size_t)ofs + 0] = (float)col;  // min = col (tril => col <= row)
        out[2 * (size_t)ofs + 1] = fk;          // max = row
        ++ofs;
        w &= w - 1;
    }
}

extern "C" void kernel_launch(void* const* d_in, const int* in_sizes, int n_in,
                              void* d_out, int out_size, void* d_ws, size_t ws_size,
                              hipStream_t stream) {
    const float* bbmin = (const float*)d_in[0];
    const float* bbmax = (const float*)d_in[1];
    const float* A = (const float*)d_in[2];
    const uint8_t* dis = (const uint8_t*)d_in[3];
    float* out = (float*)d_out;

    char* ws = (char*)d_ws;
    uint64_t* bm = (uint64_t*)(ws + BM_OFF);
    uint32_t* tileCnt = (uint32_t*)(ws + TC_OFF);

    k_main<<<TILE_BLOCKS + POSE_BLOCKS, 256, 0, stream>>>(
        bbmin, bbmax, A, dis, out, out + KBOX * 24, bm, tileCnt);
    k_compact<<<KBOX, 256, 0, stream>>>(bm, tileCnt, out + KBOX * 24);
}

// Round 13
// 21.256 us; speedup vs baseline: 8.2232x; 1.1240x over previous
//
#include <hip/hip_runtime.h>
#include <stdint.h>

#define KBOX 1024
#define EPSF 1e-4f
#define SLACK 3e-5f
#define TILE_BLOCKS 4096   // (row k, 256-col tile j): bid = k*4 + j
#define POSE_BLOCKS 4      // 4*256 = 1024 boxes -> hposed output

// ws layout (bytes):
//   0      : bm [K][16] u64    (128 KB) inside bitmask words
//   131072 : tileCnt [K][4] u32 (16 KB)  per (row, col-tile) count
#define BM_OFF 0
#define TC_OFF 131072

// double-precision analytic inverse of the affine 3x4 (rows of A) -> 12 floats
__device__ inline void inv_affine(const float r[12], float* o) {
    double m00 = r[0], m01 = r[1], m02 = r[2];
    double m10 = r[4], m11 = r[5], m12 = r[6];
    double m20 = r[8], m21 = r[9], m22 = r[10];
    double c00 = m11 * m22 - m12 * m21;
    double c01 = m12 * m20 - m10 * m22;
    double c02 = m10 * m21 - m11 * m20;
    double det = m00 * c00 + m01 * c01 + m02 * c02;
    double id = 1.0 / det;
    double i00 = c00 * id, i01 = (m02 * m21 - m01 * m22) * id, i02 = (m01 * m12 - m02 * m11) * id;
    double i10 = c01 * id, i11 = (m00 * m22 - m02 * m20) * id, i12 = (m02 * m10 - m00 * m12) * id;
    double i20 = c02 * id, i21 = (m01 * m20 - m00 * m21) * id, i22 = (m00 * m11 - m01 * m10) * id;
    double tx = r[3], ty = r[7], tz = r[11];
    o[0] = (float)i00; o[1] = (float)i01; o[2] = (float)i02;
    o[3] = (float)(-(i00 * tx + i01 * ty + i02 * tz));
    o[4] = (float)i10; o[5] = (float)i11; o[6] = (float)i12;
    o[7] = (float)(-(i10 * tx + i11 * ty + i12 * tz));
    o[8] = (float)i20; o[9] = (float)i21; o[10] = (float)i22;
    o[11] = (float)(-(i20 * tx + i21 * ty + i22 * tz));
}

__global__ void k_main(const float* __restrict__ bbmin, const float* __restrict__ bbmax,
                       const float* __restrict__ A, const uint8_t* __restrict__ disB,
                       float* __restrict__ out_hposed, float* __restrict__ out_pairs,
                       uint64_t* __restrict__ bm, uint32_t* __restrict__ tileCnt) {
    int bid = blockIdx.x;
    int t = threadIdx.x;

    if (bid >= TILE_BLOCKS) {  // pose blocks: write hposed (output 0)
        int k = (bid - TILE_BLOCKS) * 256 + t;
        float r[12];
#pragma unroll
        for (int i = 0; i < 3; ++i) {
            float4 a4 = *(const float4*)(A + (size_t)k * 16 + i * 4);
            r[i * 4 + 0] = a4.x; r[i * 4 + 1] = a4.y; r[i * 4 + 2] = a4.z; r[i * 4 + 3] = a4.w;
        }
        float bmn[3], bmx[3];
#pragma unroll
        for (int i = 0; i < 3; ++i) { bmn[i] = bbmin[k * 3 + i]; bmx[i] = bbmax[k * 3 + i]; }
#pragma unroll
        for (int c = 0; c < 8; ++c) {
            float cx = ((c >> 2) & 1) ? bmx[0] : bmn[0];
            float cy = ((c >> 1) & 1) ? bmx[1] : bmn[1];
            float cz = (c & 1) ? bmx[2] : bmn[2];
#pragma unroll
            for (int i = 0; i < 3; ++i)
                out_hposed[(size_t)k * 24 + c * 3 + i] =
                    r[i * 4 + 0] * cx + r[i * 4 + 1] * cy + r[i * 4 + 2] * cz + r[i * 4 + 3];
        }
        return;
    }

    // ---- tile block: row k, cols j*256..j*256+255 — NO mid-kernel barrier ----
    int k = bid >> 2, j = bid & 3;
    int lane = t & 63, wave = t >> 6;

    // fill this block's 2KB slice of the pair region with -1
    ((float2*)out_pairs)[(size_t)bid * 256 + t] = make_float2(-1.f, -1.f);

    if (j * 256 > k) {  // inactive tile: publish zero counts, done
        if (t < 4) tileCnt[(size_t)k * 4 + j] = 0;  // note: one u32 per (k,j)
        return;
    }
    int l = j * 256 + t;

    // dis layout detect, per-wave (no LDS/sync): int32 0/1 data has all high
    // bytes zero in the first 256 B; random bools don't
    uint32_t dw = ((const uint32_t*)disB)[lane];
    const bool isBool = __ballot((dw & 0xFFFFFF00u) != 0 ? 1 : 0) != 0ull;

    // row data: broadcast loads (all lanes same address -> L1 line hit)
    float rk[12];
#pragma unroll
    for (int i = 0; i < 3; ++i) {
        float4 a4 = *(const float4*)(A + (size_t)k * 16 + i * 4);
        rk[i * 4 + 0] = a4.x; rk[i * 4 + 1] = a4.y; rk[i * 4 + 2] = a4.z; rk[i * 4 + 3] = a4.w;
    }
    float bmnk[3], bmxk[3];
#pragma unroll
    for (int i = 0; i < 3; ++i) { bmnk[i] = bbmin[k * 3 + i]; bmxk[i] = bbmax[k * 3 + i]; }
    // row world AABB via |R|·h (exact AABB of the affine image, like corner hull)
    float wmnk[3], wmxk[3];
    {
        float cx = 0.5f * (bmnk[0] + bmxk[0]), hx = 0.5f * (bmxk[0] - bmnk[0]);
        float cy = 0.5f * (bmnk[1] + bmxk[1]), hy = 0.5f * (bmxk[1] - bmnk[1]);
        float cz = 0.5f * (bmnk[2] + bmxk[2]), hz = 0.5f * (bmxk[2] - bmnk[2]);
#pragma unroll
        for (int i = 0; i < 3; ++i) {
            float c = rk[i * 4 + 0] * cx + rk[i * 4 + 1] * cy + rk[i * 4 + 2] * cz + rk[i * 4 + 3];
            float h = fabsf(rk[i * 4 + 0]) * hx + fabsf(rk[i * 4 + 1]) * hy + fabsf(rk[i * 4 + 2]) * hz;
            wmnk[i] = c - h - SLACK;
            wmxk[i] = c + h + SLACK;
        }
    }

    // col data
    float rl[12];
#pragma unroll
    for (int i = 0; i < 3; ++i) {
        float4 a4 = *(const float4*)(A + (size_t)l * 16 + i * 4);
        rl[i * 4 + 0] = a4.x; rl[i * 4 + 1] = a4.y; rl[i * 4 + 2] = a4.z; rl[i * 4 + 3] = a4.w;
    }
    float bmnl[3], bmxl[3];
#pragma unroll
    for (int i = 0; i < 3; ++i) { bmnl[i] = bbmin[l * 3 + i]; bmxl[i] = bbmax[l * 3 + i]; }
    float wcl[3], whl[3];
    {
        float cx = 0.5f * (bmnl[0] + bmxl[0]), hx = 0.5f * (bmxl[0] - bmnl[0]);
        float cy = 0.5f * (bmnl[1] + bmxl[1]), hy = 0.5f * (bmxl[1] - bmnl[1]);
        float cz = 0.5f * (bmnl[2] + bmxl[2]), hz = 0.5f * (bmxl[2] - bmnl[2]);
#pragma unroll
        for (int i = 0; i < 3; ++i) {
            wcl[i] = rl[i * 4 + 0] * cx + rl[i * 4 + 1] * cy + rl[i * 4 + 2] * cz + rl[i * 4 + 3];
            whl[i] = fabsf(rl[i * 4 + 0]) * hx + fabsf(rl[i * 4 + 1]) * hy + fabsf(rl[i * 4 + 2]) * hz;
        }
    }

    bool cand = false;
    if (l <= k) {
        cand = (wcl[0] - whl[0] <= wmxk[0]) & (wmnk[0] <= wcl[0] + whl[0]) &
               (wcl[1] - whl[1] <= wmxk[1]) & (wmnk[1] <= wcl[1] + whl[1]) &
               (wcl[2] - whl[2] <= wmxk[2]) & (wmnk[2] <= wcl[2] + whl[2]);
    }
    bool bit = false, dA = false, dB = false;
    if (cand) {  // dis bits only for AABB candidates (~1% of pairs)
        if (isBool) {
            dA = disB[(size_t)k * KBOX + l] != 0;
            dB = disB[(size_t)l * KBOX + k] != 0;
        } else {
            const int* disI = (const int*)disB;
            dA = disI[(size_t)k * KBOX + l] != 0;
            dB = disI[(size_t)l * KBOX + k] != 0;
        }
    }
    if (cand && (dA | dB)) {  // rare heavy path: per-lane, formulas identical
        if (dA) {  // corners of l into frame k
            float bk[12];
            inv_affine(rk, bk);
            bool rawA = false;
#pragma unroll
            for (int c = 0; c < 8; ++c) {
                float cx = ((c >> 2) & 1) ? bmxl[0] : bmnl[0];
                float cy = ((c >> 1) & 1) ? bmxl[1] : bmnl[1];
                float cz = (c & 1) ? bmxl[2] : bmnl[2];
                float px = rl[0] * cx + rl[1] * cy + rl[2] * cz + rl[3];
                float py = rl[4] * cx + rl[5] * cy + rl[6] * cz + rl[7];
                float pz = rl[8] * cx + rl[9] * cy + rl[10] * cz + rl[11];
                float x = bk[0] * px + bk[1] * py + bk[2] * pz + bk[3];
                float y = bk[4] * px + bk[5] * py + bk[6] * pz + bk[7];
                float z = bk[8] * px + bk[9] * py + bk[10] * pz + bk[11];
                rawA = rawA || (x > bmnk[0] + EPSF && x < bmxk[0] - EPSF &&
                                y > bmnk[1] + EPSF && y < bmxk[1] - EPSF &&
                                z > bmnk[2] + EPSF && z < bmxk[2] - EPSF);
            }
            bit = rawA;
        }
        if (dB && !bit) {  // corners of k into frame l
            float bl[12];
            inv_affine(rl, bl);
            bool rawB = false;
#pragma unroll
            for (int c = 0; c < 8; ++c) {
                float cx = ((c >> 2) & 1) ? bmxk[0] : bmnk[0];
                float cy = ((c >> 1) & 1) ? bmxk[1] : bmnk[1];
                float cz = (c & 1) ? bmxk[2] : bmnk[2];
                float px = rk[0] * cx + rk[1] * cy + rk[2] * cz + rk[3];
                float py = rk[4] * cx + rk[5] * cy + rk[6] * cz + rk[7];
                float pz = rk[8] * cx + rk[9] * cy + rk[10] * cz + rk[11];
                float x = bl[0] * px + bl[1] * py + bl[2] * pz + bl[3];
                float y = bl[4] * px + bl[5] * py + bl[6] * pz + bl[7];
                float z = bl[8] * px + bl[9] * py + bl[10] * pz + bl[11];
                rawB = rawB || (x > bmnl[0] + EPSF && x < bmxl[0] - EPSF &&
                                y > bmnl[1] + EPSF && y < bmxl[1] - EPSF &&
                                z > bmnl[2] + EPSF && z < bmxl[2] - EPSF);
            }
            bit = rawB;
        }
    }
    uint64_t word = __ballot(bit ? 1 : 0);
    __shared__ uint32_t wcnt[4];
    if (lane == 0) {
        bm[(size_t)k * 16 + j * 4 + wave] = word;
        wcnt[wave] = (uint32_t)__popcll(word);
    }
    __syncthreads();  // only barrier in the kernel; all waves arrive together
    if (t == 0) tileCnt[(size_t)k * 4 + j] = wcnt[0] + wcnt[1] + wcnt[2] + wcnt[3];
}

__global__ void k_compact(const uint64_t* __restrict__ bm,
                          const uint32_t* __restrict__ tileCnt, float* __restrict__ out) {
    int k = blockIdx.x;
    int t = threadIdx.x;  // 256 threads
    int wave = t >> 6, lane = t & 63;
    __shared__ uint32_t ws4[4];
    // start = sum of row counts for rows < k (constant trip count, loads in flight)
    uint32_t s = 0;
#pragma unroll
    for (int rr = 0; rr < 4; ++rr) {
        int row = t + rr * 256;
        uint4 c4 = *(const uint4*)(tileCnt + (size_t)row * 4);
        uint32_t v = c4.x + c4.y + c4.z + c4.w;
        s += (row < k) ? v : 0u;
    }
#pragma unroll
    for (int off = 32; off > 0; off >>= 1) s += __shfl_xor(s, off);
    if (lane == 0) ws4[wave] = s;
    __syncthreads();
    if (t >= 64) return;  // wave 0 finishes the row
    uint32_t start = ws4[0] + ws4[1] + ws4[2] + ws4[3];

    // only words with t*64 <= k are written by k_main; mask the rest
    uint64_t w = (t < 16 && t * 64 <= k) ? bm[(size_t)k * 16 + t] : 0ull;
    int c = (int)__popcll(w);
    int p = c;
#pragma unroll
    for (int off = 1; off < 64; off <<= 1) {
        int u = __shfl_up(p, off);
        if (t >= off) p += u;
    }
    int ofs = (int)start + (p - c);
    float fk = (float)k;
    while (w) {
        int b = __builtin_ctzll(w);
        int col = t * 64 + b;
        out[2 * (size_t)ofs + 0] = (float)col;  // min = col (tril => col <= row)
        out[2 * (size_t)ofs + 1] = fk;          // max = row
        ++ofs;
        w &= w - 1;
    }
}

extern "C" void kernel_launch(void* const* d_in, const int* in_sizes, int n_in,
                              void* d_out, int out_size, void* d_ws, size_t ws_size,
                              hipStream_t stream) {
    const float* bbmin = (const float*)d_in[0];
    const float* bbmax = (const float*)d_in[1];
    const float* A = (const float*)d_in[2];
    const uint8_t* dis = (const uint8_t*)d_in[3];
    float* out = (float*)d_out;

    char* ws = (char*)d_ws;
    uint64_t* bm = (uint64_t*)(ws + BM_OFF);
    uint32_t* tileCnt = (uint32_t*)(ws + TC_OFF);

    k_main<<<TILE_BLOCKS + POSE_BLOCKS, 256, 0, stream>>>(
        bbmin, bbmax, A, dis, out, out + KBOX * 24, bm, tileCnt);
    k_compact<<<KBOX, 256, 0, stream>>>(bm, tileCnt, out + KBOX * 24);
}

// Round 14
// 19.152 us; speedup vs baseline: 9.1265x; 1.1098x over previous
//
#include <hip/hip_runtime.h>
#include <stdint.h>

#define KBOX 1024
#define EPSF 1e-4f
#define SLACK 3e-5f
#define ACT_TILES 2560     // triangular: 256*1 + 256*2 + 256*3 + 256*4
#define POSE_BLOCKS 4      // 4*256 = 1024 boxes -> hposed output

// ws layout (bytes):
//   0      : bm [K][16] u64    (128 KB) inside bitmask words (active words only)
//   131072 : tileCnt [K][4] u32 (16 KB)  only j*256<=k entries written/read
#define BM_OFF 0
#define TC_OFF 131072

// double-precision analytic inverse of the affine 3x4 (rows of A) -> 12 floats
__device__ inline void inv_affine(const float r[12], float* o) {
    double m00 = r[0], m01 = r[1], m02 = r[2];
    double m10 = r[4], m11 = r[5], m12 = r[6];
    double m20 = r[8], m21 = r[9], m22 = r[10];
    double c00 = m11 * m22 - m12 * m21;
    double c01 = m12 * m20 - m10 * m22;
    double c02 = m10 * m21 - m11 * m20;
    double det = m00 * c00 + m01 * c01 + m02 * c02;
    double id = 1.0 / det;
    double i00 = c00 * id, i01 = (m02 * m21 - m01 * m22) * id, i02 = (m01 * m12 - m02 * m11) * id;
    double i10 = c01 * id, i11 = (m00 * m22 - m02 * m20) * id, i12 = (m02 * m10 - m00 * m12) * id;
    double i20 = c02 * id, i21 = (m01 * m20 - m00 * m21) * id, i22 = (m00 * m11 - m01 * m10) * id;
    double tx = r[3], ty = r[7], tz = r[11];
    o[0] = (float)i00; o[1] = (float)i01; o[2] = (float)i02;
    o[3] = (float)(-(i00 * tx + i01 * ty + i02 * tz));
    o[4] = (float)i10; o[5] = (float)i11; o[6] = (float)i12;
    o[7] = (float)(-(i10 * tx + i11 * ty + i12 * tz));
    o[8] = (float)i20; o[9] = (float)i21; o[10] = (float)i22;
    o[11] = (float)(-(i20 * tx + i21 * ty + i22 * tz));
}

__global__ void k_main(const float* __restrict__ bbmin, const float* __restrict__ bbmax,
                       const float* __restrict__ A, const uint8_t* __restrict__ disB,
                       float* __restrict__ out_hposed,
                       uint64_t* __restrict__ bm, uint32_t* __restrict__ tileCnt) {
    int bid = blockIdx.x;
    int t = threadIdx.x;

    if (bid >= ACT_TILES) {  // pose blocks: write hposed (output 0)
        int k = (bid - ACT_TILES) * 256 + t;
        float r[12];
#pragma unroll
        for (int i = 0; i < 3; ++i) {
            float4 a4 = *(const float4*)(A + (size_t)k * 16 + i * 4);
            r[i * 4 + 0] = a4.x; r[i * 4 + 1] = a4.y; r[i * 4 + 2] = a4.z; r[i * 4 + 3] = a4.w;
        }
        float bmn[3], bmx[3];
#pragma unroll
        for (int i = 0; i < 3; ++i) { bmn[i] = bbmin[k * 3 + i]; bmx[i] = bbmax[k * 3 + i]; }
#pragma unroll
        for (int c = 0; c < 8; ++c) {
            float cx = ((c >> 2) & 1) ? bmx[0] : bmn[0];
            float cy = ((c >> 1) & 1) ? bmx[1] : bmn[1];
            float cz = (c & 1) ? bmx[2] : bmn[2];
#pragma unroll
            for (int i = 0; i < 3; ++i)
                out_hposed[(size_t)k * 24 + c * 3 + i] =
                    r[i * 4 + 0] * cx + r[i * 4 + 1] * cy + r[i * 4 + 2] * cz + r[i * 4 + 3];
        }
        return;
    }

    // triangular bid -> (row k, col tile j); only below-diagonal tiles exist
    int k, j;
    if (bid < 256)       { k = bid;                      j = 0; }
    else if (bid < 768)  { k = 256 + ((bid - 256) >> 1); j = (bid - 256) & 1; }
    else if (bid < 1536) { k = 512 + (bid - 768) / 3;    j = (bid - 768) % 3; }
    else                 { k = 768 + ((bid - 1536) >> 2);j = (bid - 1536) & 3; }
    int lane = t & 63, wave = t >> 6;
    int l = j * 256 + t;

    // dis layout detect, per-wave (no LDS/sync)
    uint32_t dw = ((const uint32_t*)disB)[lane];
    const bool isBool = __ballot((dw & 0xFFFFFF00u) != 0 ? 1 : 0) != 0ull;

    // row data: broadcast loads (all lanes same address -> L1 line hit)
    float rk[12];
#pragma unroll
    for (int i = 0; i < 3; ++i) {
        float4 a4 = *(const float4*)(A + (size_t)k * 16 + i * 4);
        rk[i * 4 + 0] = a4.x; rk[i * 4 + 1] = a4.y; rk[i * 4 + 2] = a4.z; rk[i * 4 + 3] = a4.w;
    }
    float bmnk[3], bmxk[3];
#pragma unroll
    for (int i = 0; i < 3; ++i) { bmnk[i] = bbmin[k * 3 + i]; bmxk[i] = bbmax[k * 3 + i]; }
    float wmnk[3], wmxk[3];
    {
        float cx = 0.5f * (bmnk[0] + bmxk[0]), hx = 0.5f * (bmxk[0] - bmnk[0]);
        float cy = 0.5f * (bmnk[1] + bmxk[1]), hy = 0.5f * (bmxk[1] - bmnk[1]);
        float cz = 0.5f * (bmnk[2] + bmxk[2]), hz = 0.5f * (bmxk[2] - bmnk[2]);
#pragma unroll
        for (int i = 0; i < 3; ++i) {
            float c = rk[i * 4 + 0] * cx + rk[i * 4 + 1] * cy + rk[i * 4 + 2] * cz + rk[i * 4 + 3];
            float h = fabsf(rk[i * 4 + 0]) * hx + fabsf(rk[i * 4 + 1]) * hy + fabsf(rk[i * 4 + 2]) * hz;
            wmnk[i] = c - h - SLACK;
            wmxk[i] = c + h + SLACK;
        }
    }

    // col data
    float rl[12];
#pragma unroll
    for (int i = 0; i < 3; ++i) {
        float4 a4 = *(const float4*)(A + (size_t)l * 16 + i * 4);
        rl[i * 4 + 0] = a4.x; rl[i * 4 + 1] = a4.y; rl[i * 4 + 2] = a4.z; rl[i * 4 + 3] = a4.w;
    }
    float bmnl[3], bmxl[3];
#pragma unroll
    for (int i = 0; i < 3; ++i) { bmnl[i] = bbmin[l * 3 + i]; bmxl[i] = bbmax[l * 3 + i]; }
    float wcl[3], whl[3];
    {
        float cx = 0.5f * (bmnl[0] + bmxl[0]), hx = 0.5f * (bmxl[0] - bmnl[0]);
        float cy = 0.5f * (bmnl[1] + bmxl[1]), hy = 0.5f * (bmxl[1] - bmnl[1]);
        float cz = 0.5f * (bmnl[2] + bmxl[2]), hz = 0.5f * (bmxl[2] - bmnl[2]);
#pragma unroll
        for (int i = 0; i < 3; ++i) {
            wcl[i] = rl[i * 4 + 0] * cx + rl[i * 4 + 1] * cy + rl[i * 4 + 2] * cz + rl[i * 4 + 3];
            whl[i] = fabsf(rl[i * 4 + 0]) * hx + fabsf(rl[i * 4 + 1]) * hy + fabsf(rl[i * 4 + 2]) * hz;
        }
    }

    bool cand = false;
    if (l <= k) {
        cand = (wcl[0] - whl[0] <= wmxk[0]) & (wmnk[0] <= wcl[0] + whl[0]) &
               (wcl[1] - whl[1] <= wmxk[1]) & (wmnk[1] <= wcl[1] + whl[1]) &
               (wcl[2] - whl[2] <= wmxk[2]) & (wmnk[2] <= wcl[2] + whl[2]);
    }
    bool bit = false, dA = false, dB = false;
    if (cand) {  // dis bits only for AABB candidates (~1% of pairs)
        if (isBool) {
            dA = disB[(size_t)k * KBOX + l] != 0;
            dB = disB[(size_t)l * KBOX + k] != 0;
        } else {
            const int* disI = (const int*)disB;
            dA = disI[(size_t)k * KBOX + l] != 0;
            dB = disI[(size_t)l * KBOX + k] != 0;
        }
    }
    if (cand && (dA | dB)) {  // rare heavy path: per-lane, formulas identical
        if (dA) {  // corners of l into frame k
            float bk[12];
            inv_affine(rk, bk);
            bool rawA = false;
#pragma unroll
            for (int c = 0; c < 8; ++c) {
                float cx = ((c >> 2) & 1) ? bmxl[0] : bmnl[0];
                float cy = ((c >> 1) & 1) ? bmxl[1] : bmnl[1];
                float cz = (c & 1) ? bmxl[2] : bmnl[2];
                float px = rl[0] * cx + rl[1] * cy + rl[2] * cz + rl[3];
                float py = rl[4] * cx + rl[5] * cy + rl[6] * cz + rl[7];
                float pz = rl[8] * cx + rl[9] * cy + rl[10] * cz + rl[11];
                float x = bk[0] * px + bk[1] * py + bk[2] * pz + bk[3];
                float y = bk[4] * px + bk[5] * py + bk[6] * pz + bk[7];
                float z = bk[8] * px + bk[9] * py + bk[10] * pz + bk[11];
                rawA = rawA || (x > bmnk[0] + EPSF && x < bmxk[0] - EPSF &&
                                y > bmnk[1] + EPSF && y < bmxk[1] - EPSF &&
                                z > bmnk[2] + EPSF && z < bmxk[2] - EPSF);
            }
            bit = rawA;
        }
        if (dB && !bit) {  // corners of k into frame l
            float bl[12];
            inv_affine(rl, bl);
            bool rawB = false;
#pragma unroll
            for (int c = 0; c < 8; ++c) {
                float cx = ((c >> 2) & 1) ? bmxk[0] : bmnk[0];
                float cy = ((c >> 1) & 1) ? bmxk[1] : bmnk[1];
                float cz = (c & 1) ? bmxk[2] : bmnk[2];
                float px = rk[0] * cx + rk[1] * cy + rk[2] * cz + rk[3];
                float py = rk[4] * cx + rk[5] * cy + rk[6] * cz + rk[7];
                float pz = rk[8] * cx + rk[9] * cy + rk[10] * cz + rk[11];
                float x = bl[0] * px + bl[1] * py + bl[2] * pz + bl[3];
                float y = bl[4] * px + bl[5] * py + bl[6] * pz + bl[7];
                float z = bl[8] * px + bl[9] * py + bl[10] * pz + bl[11];
                rawB = rawB || (x > bmnl[0] + EPSF && x < bmxl[0] - EPSF &&
                                y > bmnl[1] + EPSF && y < bmxl[1] - EPSF &&
                                z > bmnl[2] + EPSF && z < bmxl[2] - EPSF);
            }
            bit = rawB;
        }
    }
    uint64_t word = __ballot(bit ? 1 : 0);
    __shared__ uint32_t wcnt[4];
    if (lane == 0) {
        bm[(size_t)k * 16 + j * 4 + wave] = word;
        wcnt[wave] = (uint32_t)__popcll(word);
    }
    __syncthreads();
    if (t == 0) tileCnt[(size_t)k * 4 + j] = wcnt[0] + wcnt[1] + wcnt[2] + wcnt[3];
}

// 256 blocks x 256 threads: block b owns rows 4b..4b+3 (one per wave) and a
// 1/256 slice of the complement -1 fill.
__global__ void k_compact(const uint64_t* __restrict__ bm,
                          const uint32_t* __restrict__ tileCnt, float* __restrict__ out) {
    int b = blockIdx.x;
    int t = threadIdx.x;
    int wave = t >> 6, lane = t & 63;
    int k0 = 4 * b;
    __shared__ uint32_t baseW[4], totW[4], rowc[4];

    // per-thread: 4 strided rows; mask tile components by validity (j*256<=row)
    uint32_t sm = 0, st = 0;
#pragma unroll
    for (int rr = 0; rr < 4; ++rr) {
        int row = t + rr * 256;
        uint4 c4 = *(const uint4*)(tileCnt + (size_t)row * 4);
        uint32_t v = c4.x + ((row >= 256) ? c4.y : 0u) + ((row >= 512) ? c4.z : 0u) +
                     ((row >= 768) ? c4.w : 0u);
        sm += (row < k0) ? v : 0u;
        st += v;
    }
#pragma unroll
    for (int off = 32; off > 0; off >>= 1) { sm += __shfl_xor(sm, off); st += __shfl_xor(st, off); }
    if (lane == 0) { baseW[wave] = sm; totW[wave] = st; }
    if (t < 4) {  // in-block row counts
        int row = k0 + t;
        uint4 c4 = *(const uint4*)(tileCnt + (size_t)row * 4);
        rowc[t] = c4.x + ((row >= 256) ? c4.y : 0u) + ((row >= 512) ? c4.z : 0u) +
                  ((row >= 768) ? c4.w : 0u);
    }
    __syncthreads();
    uint32_t base = baseW[0] + baseW[1] + baseW[2] + baseW[3];
    uint32_t total = totW[0] + totW[1] + totW[2] + totW[3];

    // complement fill: positions [total, K*K) in float2 units get (-1,-1);
    // pair writes below cover [0, total) exactly -> disjoint, race-free.
    float2* o2 = (float2*)out;
    for (uint32_t i = total + (uint32_t)b * 256 + t; i < (uint32_t)(KBOX * KBOX); i += 256 * 256)
        o2[i] = make_float2(-1.f, -1.f);

    // wave w compacts row k0+w
    uint32_t startw = base;
#pragma unroll
    for (int r = 0; r < 4; ++r)
        if (r < wave) startw += rowc[r];
    int k = k0 + wave;
    uint64_t w = (lane < 16 && lane * 64 <= k) ? bm[(size_t)k * 16 + lane] : 0ull;
    int c = (int)__popcll(w);
    int p = c;
#pragma unroll
    for (int off = 1; off < 64; off <<= 1) {
        int u = __shfl_up(p, off);
        if (lane >= off) p += u;
    }
    int ofs = (int)startw + (p - c);
    float fk = (float)k;
    while (w) {
        int bpos = __builtin_ctzll(w);
        int col = lane * 64 + bpos;
        out[2 * (size_t)ofs + 0] = (float)col;  // min = col (tril => col <= row)
        out[2 * (size_t)ofs + 1] = fk;          // max = row
        ++ofs;
        w &= w - 1;
    }
}

extern "C" void kernel_launch(void* const* d_in, const int* in_sizes, int n_in,
                              void* d_out, int out_size, void* d_ws, size_t ws_size,
                              hipStream_t stream) {
    const float* bbmin = (const float*)d_in[0];
    const float* bbmax = (const float*)d_in[1];
    const float* A = (const float*)d_in[2];
    const uint8_t* dis = (const uint8_t*)d_in[3];
    float* out = (float*)d_out;

    char* ws = (char*)d_ws;
    uint64_t* bm = (uint64_t*)(ws + BM_OFF);
    uint32_t* tileCnt = (uint32_t*)(ws + TC_OFF);

    k_main<<<ACT_TILES + POSE_BLOCKS, 256, 0, stream>>>(
        bbmin, bbmax, A, dis, out, bm, tileCnt);
    k_compact<<<256, 256, 0, stream>>>(bm, tileCnt, out + KBOX * 24);
}